// Round 3
// baseline (157.919 us; speedup 1.0000x reference)
//
#include <hip/hip_runtime.h>

typedef _Float16 f16x8 __attribute__((ext_vector_type(8)));
typedef float floatx4 __attribute__((ext_vector_type(4)));

#define NPTS   10240          // 1024*10 evaluation points
#define SSTEPS 33             // CC nodes (NB_STEPS+1)
#define MTOT   (NPTS*SSTEPS)  // 337920 rows, s-major: row = s*NPTS + n
#define M_TILE 96
#define NBLK_MAIN (MTOT / M_TILE)   // 3520

// ws byte offsets
#define WS_STEPS 0        // 33 f32
#define WS_CCW   256      // 33 f32
#define WS_X     512      // 10240 f32
#define WS_W2IMG 65536    // 131072 B: f16 W2, [chunk][kslice] pre-swizzled LDS images
#define WS_G     196608   // 337920 f32 integrand values

__device__ __forceinline__ unsigned short f2h_bits(float f) {
  union { _Float16 h; unsigned short u; } c;
  c.h = (_Float16)f;            // v_cvt_f16_f32, RNE
  return c.u;
}

__device__ __forceinline__ float elu1(float v) {
  return v > 0.f ? v : __expf(v) - 1.f;
}

// ---------------------------------------------------------------------------
// prep: block 0..255 -> W2 fp32 -> f16 swizzled image; block 256 -> CC const;
//       blocks 257..260 -> log-softmax of logits into x.
// ---------------------------------------------------------------------------
__global__ void k_prep(const float* __restrict__ logits,
                       const float* __restrict__ W2,
                       unsigned char* __restrict__ ws)
{
  const int bid = blockIdx.x, tid = threadIdx.x;
  if (bid < 256) {
    // element e = k*256 + j  (W2[k][j], k = K dim (input h), j = N dim)
    int e = (bid << 8) + tid;
    int k = e >> 8, j = e & 255;
    int chunk = j >> 7, nl = j & 127, ks = k >> 5, kk = k & 31;
    // slice image: row nl (64B), 16B-chunk index (kk>>3) XOR ((nl>>1)&3), elem (kk&7)
    unsigned off = (unsigned)(chunk * 8 + ks) * 8192u + (unsigned)nl * 64u
                 + ((((kk >> 3) ^ ((nl >> 1) & 3)) << 4) | ((kk & 7) << 1));
    *(unsigned short*)(ws + WS_W2IMG + off) = f2h_bits(W2[e]);
  } else if (bid == 256) {
    if (tid <= 32) {
      const double pi = 3.141592653589793238462643383279502884;
      float* steps = (float*)(ws + WS_STEPS);
      float* ccw   = (float*)(ws + WS_CCW);
      steps[tid] = (float)cos((double)tid * pi / 32.0);
      double acc = 0.0;
      for (int i = 0; i <= 32; i += 2) {           // odd i have Wv=0
        double wv = (i == 0) ? 1.0 : 2.0 / (1.0 - (double)(i * i));
        double L  = cos((double)(i * tid) * pi / 32.0);
        if (tid == 0)  L = 0.5;
        if (tid == 32) L *= 0.5;
        acc += L * wv;
      }
      ccw[tid] = (float)(acc * (1.0 / 16.0));      // * 2/nb
    }
  } else {
    int r = ((bid - 257) << 8) + tid;              // 0..1023
    const float* row = logits + r * 10;
    float v[10]; float m = -3.0e38f;
    #pragma unroll
    for (int c = 0; c < 10; ++c) { v[c] = row[c]; m = fmaxf(m, v[c]); }
    float s = 0.f;
    #pragma unroll
    for (int c = 0; c < 10; ++c) s += __expf(v[c] - m);
    float lse = m + __logf(s);
    float* x = (float*)(ws + WS_X);
    #pragma unroll
    for (int c = 0; c < 10; ++c) x[r * 10 + c] = v[c] - lse;
  }
}

// ---------------------------------------------------------------------------
// main: per block 96 rows. h1 (96x256 f16) in LDS; W2 staged in 8KB k-slices;
// 16x16x32 f16 MFMA, 2x2 waves (48x64 per wave); fused elu/W3 epilogue -> g.
// Cross-wave (wn) column-half reduction via LDS before the g write.
// ---------------------------------------------------------------------------
__global__ __launch_bounds__(256, 2) void k_main(
    const unsigned char* __restrict__ ws,
    const float* __restrict__ W1, const float* __restrict__ b1,
    const float* __restrict__ b2, const float* __restrict__ W3,
    const float* __restrict__ b3)
{
  __shared__ unsigned char smem[96 * 512 + 8192] __attribute__((aligned(16)));  // 57344
  const int tid  = threadIdx.x;
  const int lane = tid & 63, wid = tid >> 6;
  const int wm = wid >> 1, wn = wid & 1;
  const int l15 = lane & 15, l4 = lane >> 4;

  const float* xs    = (const float*)(ws + WS_X);
  const float* steps = (const float*)(ws + WS_STEPS);
  const unsigned char* w2img = ws + WS_W2IMG;
  float* g_out = (float*)(const_cast<unsigned char*>(ws) + WS_G);

  const int row_base = blockIdx.x * M_TILE;

  // ---- layer 1: h1[r][k] = elu(t_r * W1[k] + b1[k]) -> f16 LDS (swizzled) ----
  {
    const int k0 = (tid & 31) << 3;
    float w1v[8], b1v[8];
    *(float4*)&w1v[0] = *(const float4*)(W1 + k0);
    *(float4*)&w1v[4] = *(const float4*)(W1 + k0 + 4);
    *(float4*)&b1v[0] = *(const float4*)(b1 + k0);
    *(float4*)&b1v[4] = *(const float4*)(b1 + k0 + 4);
    #pragma unroll
    for (int p = 0; p < 12; ++p) {
      int r  = p * 8 + (tid >> 5);
      int rg = row_base + r;
      int s  = rg / NPTS;
      int n  = rg - s * NPTS;
      float t = xs[n] * (steps[s] + 1.f) * 0.5f;
      union { unsigned short u[8]; uint4 q; } pk;
      #pragma unroll
      for (int jj = 0; jj < 8; ++jj)
        pk.u[jj] = f2h_bits(elu1(fmaf(t, w1v[jj], b1v[jj])));
      *(uint4*)(smem + r * 512 + (((tid & 31) ^ (r & 7)) << 4)) = pk.q;
    }
  }

  float pacc[3][4];
  #pragma unroll
  for (int a = 0; a < 3; ++a)
    #pragma unroll
    for (int q = 0; q < 4; ++q) pacc[a][q] = 0.f;

  for (int chunk = 0; chunk < 2; ++chunk) {
    floatx4 acc[3][4];
    #pragma unroll
    for (int a = 0; a < 3; ++a)
      #pragma unroll
      for (int q = 0; q < 4; ++q) acc[a][q] = floatx4{0.f, 0.f, 0.f, 0.f};

    for (int ks = 0; ks < 8; ++ks) {
      // stage W2 k-slice (8KB, pre-swizzled image) via registers
      const uint4* src = (const uint4*)(w2img + (chunk * 8 + ks) * 8192);
      uint4 s0 = src[tid];
      uint4 s1 = src[tid + 256];
      __syncthreads();                       // prior slice reads complete
      ((uint4*)(smem + 49152))[tid]       = s0;
      ((uint4*)(smem + 49152))[tid + 256] = s1;
      __syncthreads();                       // slice visible

      f16x8 af[3], bfr[4];
      #pragma unroll
      for (int ai = 0; ai < 3; ++ai) {
        int r  = wm * 48 + ai * 16 + l15;
        int ck = ks * 4 + l4;
        af[ai] = *(const f16x8*)(smem + r * 512 + ((ck ^ (r & 7)) << 4));
      }
      #pragma unroll
      for (int bj = 0; bj < 4; ++bj) {
        int nl = wn * 64 + bj * 16 + l15;
        bfr[bj] = *(const f16x8*)(smem + 49152 + nl * 64 +
                                  ((l4 ^ ((nl >> 1) & 3)) << 4));
      }
      #pragma unroll
      for (int ai = 0; ai < 3; ++ai)
        #pragma unroll
        for (int bj = 0; bj < 4; ++bj)
          acc[ai][bj] = __builtin_amdgcn_mfma_f32_16x16x32_f16(
              af[ai], bfr[bj], acc[ai][bj], 0, 0, 0);
    }

    // fused epilogue: h2 = elu(acc + b2); pacc += h2 * W3  (this wave's cols)
    const int cw = chunk * 128 + wn * 64;
    #pragma unroll
    for (int bj = 0; bj < 4; ++bj) {
      int col = cw + bj * 16 + l15;
      float b2v = b2[col], w3v = W3[col];
      #pragma unroll
      for (int ai = 0; ai < 3; ++ai)
        #pragma unroll
        for (int rr = 0; rr < 4; ++rr)
          pacc[ai][rr] = fmaf(elu1(acc[ai][bj][rr] + b2v), w3v, pacc[ai][rr]);
    }
  }

  // ---- reduce: within-wave over 16 col-lanes, then ACROSS the wn pair ----
  __syncthreads();                       // all LDS A/W2 reads complete; reuse smem
  float* part = (float*)smem;            // [wid][48]
  #pragma unroll
  for (int ai = 0; ai < 3; ++ai)
    #pragma unroll
    for (int rr = 0; rr < 4; ++rr) {
      float v = pacc[ai][rr];
      v += __shfl_xor(v, 1);
      v += __shfl_xor(v, 2);
      v += __shfl_xor(v, 4);
      v += __shfl_xor(v, 8);
      if (l15 == 0) part[wid * 48 + ai * 16 + l4 * 4 + rr] = v;
    }
  __syncthreads();
  if (tid < 96) {
    int wmr = tid / 48, r = tid - wmr * 48;
    float o = part[(wmr * 2) * 48 + r] + part[(wmr * 2 + 1) * 48 + r] + b3[0];
    g_out[row_base + wmr * 48 + r] = elu1(o) + 1.f;
  }
}

// ---------------------------------------------------------------------------
// reduce: out[n] = (sum_s ccw[s] * g[s,n]) * x[n]*0.5 + offset
// ---------------------------------------------------------------------------
__global__ void k_reduce(const unsigned char* __restrict__ ws,
                         const float* __restrict__ offset,
                         float* __restrict__ out)
{
  int i = blockIdx.x * 256 + threadIdx.x;      // 0..10239
  const float* ccw = (const float*)(ws + WS_CCW);
  const float* xs  = (const float*)(ws + WS_X);
  const float* g   = (const float*)(ws + WS_G);
  float acc = 0.f;
  #pragma unroll
  for (int s = 0; s < SSTEPS; ++s)
    acc = fmaf(ccw[s], g[s * NPTS + i], acc);
  out[i] = fmaf(acc, xs[i] * 0.5f, offset[0]);
}

extern "C" void kernel_launch(void* const* d_in, const int* in_sizes, int n_in,
                              void* d_out, int out_size, void* d_ws, size_t ws_size,
                              hipStream_t stream)
{
  const float* logits = (const float*)d_in[0];
  const float* W1     = (const float*)d_in[1];
  const float* b1     = (const float*)d_in[2];
  const float* W2     = (const float*)d_in[3];
  const float* b2     = (const float*)d_in[4];
  const float* W3     = (const float*)d_in[5];
  const float* b3     = (const float*)d_in[6];
  const float* offset = (const float*)d_in[7];
  unsigned char* ws   = (unsigned char*)d_ws;
  float* out          = (float*)d_out;

  k_prep<<<261, 256, 0, stream>>>(logits, W2, ws);
  k_main<<<NBLK_MAIN, 256, 0, stream>>>(ws, W1, b1, b2, W3, b3);
  k_reduce<<<40, 256, 0, stream>>>(ws, offset, out);
}

// Round 4
// 154.251 us; speedup vs baseline: 1.0238x; 1.0238x over previous
//
#include <hip/hip_runtime.h>

typedef _Float16 f16x8 __attribute__((ext_vector_type(8)));
typedef float floatx4 __attribute__((ext_vector_type(4)));

#define NPTS   10240          // 1024*10 evaluation points
#define SSTEPS 33             // CC nodes (NB_STEPS+1)
#define MTOT   (NPTS*SSTEPS)  // 337920 rows, s-major: row = s*NPTS + n
#define M_TILE 96
#define NBLK_MAIN (MTOT / M_TILE)   // 3520

// ws byte offsets
#define WS_STEPS 0        // 33 f32
#define WS_CCW   256      // 33 f32
#define WS_X     512      // 10240 f32
#define WS_W2IMG 65536    // 131072 B: f16 W2 as 4 quadrant LDS images (linear-copyable)
#define WS_G     196608   // 337920 f32 integrand values

__device__ __forceinline__ float elu1(float v) {
  return v > 0.f ? v : __expf(v) - 1.f;
}

// async global->LDS, 16B per lane; LDS dest = wave-uniform base + lane*16
__device__ __forceinline__ void gload_lds16(const void* g, void* l) {
  __builtin_amdgcn_global_load_lds(
      (const __attribute__((address_space(1))) unsigned int*)g,
      (__attribute__((address_space(3))) unsigned int*)l,
      16, 0, 0);
}

// ---------------------------------------------------------------------------
// prep: blocks 0..31 -> W2 quadrant images; 32 -> CC consts; 33..36 -> softmax
// Quadrant q=(c,kh): within: byte = col*256 + ((k16l ^ (col&7))<<4) + (k&7)*2
//   holding W2[(kh*128 + k16l*8 + i)*256 + c*128 + col] as f16.
// ---------------------------------------------------------------------------
__global__ void k_prep(const float* __restrict__ logits,
                       const float* __restrict__ W2,
                       unsigned char* __restrict__ ws)
{
  const int bid = blockIdx.x, tid = threadIdx.x;
  if (bid < 32) {
    int u    = (bid << 8) + tid;         // 0..8191 16B-units
    int col  = u & 127;                  // fastest -> coalesced W2 reads
    int rest = u >> 7;
    int k16l = rest & 15;
    int q    = rest >> 4;                // 0..3
    int c    = q >> 1, kh = q & 1;
    int kbase = kh * 128 + k16l * 8;
    int j     = c * 128 + col;
    union { _Float16 h[8]; uint4 v; } pk;
    #pragma unroll
    for (int i = 0; i < 8; ++i)
      pk.h[i] = (_Float16)W2[(kbase + i) * 256 + j];
    unsigned off = (unsigned)q * 32768u + (unsigned)col * 256u
                 + (unsigned)((k16l ^ (col & 7)) << 4);
    *(uint4*)(ws + WS_W2IMG + off) = pk.v;
  } else if (bid == 32) {
    if (tid <= 32) {
      const double pi = 3.141592653589793238462643383279502884;
      float* steps = (float*)(ws + WS_STEPS);
      float* ccw   = (float*)(ws + WS_CCW);
      steps[tid] = (float)cos((double)tid * pi / 32.0);
      double acc = 0.0;
      for (int i = 0; i <= 32; i += 2) {           // odd i have Wv=0
        double wv = (i == 0) ? 1.0 : 2.0 / (1.0 - (double)(i * i));
        double L  = cos((double)(i * tid) * pi / 32.0);
        if (tid == 0)  L = 0.5;
        if (tid == 32) L *= 0.5;
        acc += L * wv;
      }
      ccw[tid] = (float)(acc * (1.0 / 16.0));      // * 2/nb
    }
  } else {
    int r = ((bid - 33) << 8) + tid;               // 0..1023
    const float* row = logits + r * 10;
    float v[10]; float m = -3.0e38f;
    #pragma unroll
    for (int c = 0; c < 10; ++c) { v[c] = row[c]; m = fmaxf(m, v[c]); }
    float s = 0.f;
    #pragma unroll
    for (int c = 0; c < 10; ++c) s += __expf(v[c] - m);
    float lse = m + __logf(s);
    float* x = (float*)(ws + WS_X);
    #pragma unroll
    for (int c = 0; c < 10; ++c) x[r * 10 + c] = v[c] - lse;
  }
}

// ---------------------------------------------------------------------------
// main: 96 rows/block, 4 waves (2 wm x 2 wn). A(h1) fragments computed in
// registers per lane (no A LDS). W2 staged as 4x32KB quadrants, double-
// buffered LDS via global_load_lds; 1 barrier per quadrant.
// ---------------------------------------------------------------------------
__global__ __launch_bounds__(256, 2) void k_main(
    const unsigned char* __restrict__ ws,
    const float* __restrict__ W1, const float* __restrict__ b1,
    const float* __restrict__ b2, const float* __restrict__ W3,
    const float* __restrict__ b3)
{
  __shared__ unsigned char smem[65536] __attribute__((aligned(16)));
  const int tid  = threadIdx.x;
  const int lane = tid & 63, wid = tid >> 6;
  const int wm = wid >> 1, wn = wid & 1;
  const int l15 = lane & 15, l4 = lane >> 4;

  const float* xs    = (const float*)(ws + WS_X);
  const float* steps = (const float*)(ws + WS_STEPS);
  const unsigned char* img = ws + WS_W2IMG;
  float* g_out = (float*)(const_cast<unsigned char*>(ws) + WS_G);

  const int row_base = blockIdx.x * M_TILE;

  // ---- issue stage(0) (quadrant 0 -> buf0), 8 x 1KB per wave ----
  #pragma unroll
  for (int i = 0; i < 8; ++i) {
    int off = wid * 1024 + i * 4096;
    gload_lds16(img + off + lane * 16, smem + off);
  }

  // ---- preload epilogue constants ----
  float b2r[2][4], w3r[2][4];
  #pragma unroll
  for (int c = 0; c < 2; ++c)
    #pragma unroll
    for (int bj = 0; bj < 4; ++bj) {
      int col = c * 128 + wn * 64 + bj * 16 + l15;
      b2r[c][bj] = b2[col];
      w3r[c][bj] = W3[col];
    }

  // ---- A fragments in registers: A[ai][ks], row=wm*48+ai*16+l15, k=ks*32+l4*8+j
  f16x8 A[3][8];
  {
    float t[3];
    #pragma unroll
    for (int ai = 0; ai < 3; ++ai) {
      int rg = row_base + wm * 48 + ai * 16 + l15;
      int s = rg / NPTS, n = rg - s * NPTS;
      t[ai] = xs[n] * (steps[s] + 1.f) * 0.5f;
    }
    #pragma unroll
    for (int ks = 0; ks < 8; ++ks) {
      int k0 = ks * 32 + l4 * 8;
      float w1v[8], b1v[8];
      *(float4*)&w1v[0] = *(const float4*)(W1 + k0);
      *(float4*)&w1v[4] = *(const float4*)(W1 + k0 + 4);
      *(float4*)&b1v[0] = *(const float4*)(b1 + k0);
      *(float4*)&b1v[4] = *(const float4*)(b1 + k0 + 4);
      #pragma unroll
      for (int ai = 0; ai < 3; ++ai) {
        union { _Float16 h[8]; f16x8 v; } pk;
        #pragma unroll
        for (int j = 0; j < 8; ++j)
          pk.h[j] = (_Float16)elu1(fmaf(t[ai], w1v[j], b1v[j]));
        A[ai][ks] = pk.v;
      }
    }
  }
  __syncthreads();   // drains vmcnt(0): stage(0) landed for all waves

  float pacc[3][4];
  #pragma unroll
  for (int a = 0; a < 3; ++a)
    #pragma unroll
    for (int r = 0; r < 4; ++r) pacc[a][r] = 0.f;

  floatx4 acc[3][4];

  // ---- quadrant pipeline: q = c*2 + kh ----
  #pragma unroll
  for (int q = 0; q < 4; ++q) {
    const int buf = (q & 1) * 32768;
    if (q < 3) {                              // issue next stage -> buf^1
      const int nb = ((q + 1) & 1) * 32768;
      #pragma unroll
      for (int i = 0; i < 8; ++i) {
        int off = wid * 1024 + i * 4096;
        gload_lds16(img + (q + 1) * 32768 + off + lane * 16, smem + nb + off);
      }
    }
    if ((q & 1) == 0) {
      #pragma unroll
      for (int a = 0; a < 3; ++a)
        #pragma unroll
        for (int bj = 0; bj < 4; ++bj) acc[a][bj] = floatx4{0.f, 0.f, 0.f, 0.f};
    }
    const int kh = q & 1;
    #pragma unroll
    for (int kl = 0; kl < 4; ++kl) {
      const int ks = kh * 4 + kl;
      f16x8 bfr[4];
      #pragma unroll
      for (int bj = 0; bj < 4; ++bj) {
        int col  = wn * 64 + bj * 16 + l15;
        int unit = (kl * 4 + l4) ^ (col & 7);
        bfr[bj]  = *(const f16x8*)(smem + buf + col * 256 + (unit << 4));
      }
      #pragma unroll
      for (int ai = 0; ai < 3; ++ai)
        #pragma unroll
        for (int bj = 0; bj < 4; ++bj)
          acc[ai][bj] = __builtin_amdgcn_mfma_f32_16x16x32_f16(
              A[ai][ks], bfr[bj], acc[ai][bj], 0, 0, 0);
    }
    if (q & 1) {                              // epilogue for chunk c = q>>1
      const int c = q >> 1;
      #pragma unroll
      for (int bj = 0; bj < 4; ++bj) {
        float b2v = b2r[c][bj], w3v = w3r[c][bj];
        #pragma unroll
        for (int ai = 0; ai < 3; ++ai)
          #pragma unroll
          for (int rr = 0; rr < 4; ++rr)
            pacc[ai][rr] = fmaf(elu1(acc[ai][bj][rr] + b2v), w3v, pacc[ai][rr]);
      }
    }
    __syncthreads();
  }

  // ---- reduce: within-wave over 16 col-lanes, then across the wn pair ----
  float* part = (float*)smem;            // [wid][48], aliases buf0 (done)
  #pragma unroll
  for (int ai = 0; ai < 3; ++ai)
    #pragma unroll
    for (int rr = 0; rr < 4; ++rr) {
      float v = pacc[ai][rr];
      v += __shfl_xor(v, 1);
      v += __shfl_xor(v, 2);
      v += __shfl_xor(v, 4);
      v += __shfl_xor(v, 8);
      if (l15 == 0) part[wid * 48 + ai * 16 + l4 * 4 + rr] = v;
    }
  __syncthreads();
  if (tid < 96) {
    int wmr = tid / 48, r = tid - wmr * 48;
    float o = part[(wmr * 2) * 48 + r] + part[(wmr * 2 + 1) * 48 + r] + b3[0];
    g_out[row_base + wmr * 48 + r] = elu1(o) + 1.f;
  }
}

// ---------------------------------------------------------------------------
// reduce: out[n] = (sum_s ccw[s] * g[s,n]) * x[n]*0.5 + offset
// ---------------------------------------------------------------------------
__global__ void k_reduce(const unsigned char* __restrict__ ws,
                         const float* __restrict__ offset,
                         float* __restrict__ out)
{
  int i = blockIdx.x * 256 + threadIdx.x;      // 0..10239
  const float* ccw = (const float*)(ws + WS_CCW);
  const float* xs  = (const float*)(ws + WS_X);
  const float* g   = (const float*)(ws + WS_G);
  float acc = 0.f;
  #pragma unroll
  for (int s = 0; s < SSTEPS; ++s)
    acc = fmaf(ccw[s], g[s * NPTS + i], acc);
  out[i] = fmaf(acc, xs[i] * 0.5f, offset[0]);
}

extern "C" void kernel_launch(void* const* d_in, const int* in_sizes, int n_in,
                              void* d_out, int out_size, void* d_ws, size_t ws_size,
                              hipStream_t stream)
{
  const float* logits = (const float*)d_in[0];
  const float* W1     = (const float*)d_in[1];
  const float* b1     = (const float*)d_in[2];
  const float* W2     = (const float*)d_in[3];
  const float* b2     = (const float*)d_in[4];
  const float* W3     = (const float*)d_in[5];
  const float* b3     = (const float*)d_in[6];
  const float* offset = (const float*)d_in[7];
  unsigned char* ws   = (unsigned char*)d_ws;
  float* out          = (float*)d_out;

  k_prep<<<37, 256, 0, stream>>>(logits, W2, ws);
  k_main<<<NBLK_MAIN, 256, 0, stream>>>(ws, W1, b1, b2, W3, b3);
  k_reduce<<<40, 256, 0, stream>>>(ws, offset, out);
}

// Round 5
// 85.379 us; speedup vs baseline: 1.8496x; 1.8067x over previous
//
#include <hip/hip_runtime.h>

typedef _Float16 f16x8 __attribute__((ext_vector_type(8)));
typedef float floatx4 __attribute__((ext_vector_type(4)));

#define NPTS   10240          // 1024*10 evaluation points
#define GRID   8256           // g(t) grid points = 86 * 96
#define GM1    8255.0f
#define NBLK_MLP 86

// ws byte offsets
#define WS_STEPS 0        // 33 f32
#define WS_CCW   256      // 33 f32
#define WS_MINX  512      // 1 f32
#define WS_X     1024     // 10240 f32
#define WS_W2IMG 65536    // 131072 B: f16 W2 as 4 quadrant LDS images (linear-copyable)
#define WS_G     196608   // 8256 f32 g(t) grid values

__device__ __forceinline__ float elu1(float v) {
  return v > 0.f ? v : __expf(v) - 1.f;
}

// async global->LDS, 16B per lane; LDS dest = wave-uniform base + lane*16
__device__ __forceinline__ void gload_lds16(const void* g, void* l) {
  __builtin_amdgcn_global_load_lds(
      (const __attribute__((address_space(1))) unsigned int*)g,
      (__attribute__((address_space(3))) unsigned int*)l,
      16, 0, 0);
}

// ---------------------------------------------------------------------------
// prep: blocks 0..31 -> W2 quadrant images; 32 -> CC consts;
//       33 -> log-softmax (all 1024 rows) + global min reduce -> min_x
// ---------------------------------------------------------------------------
__global__ void k_prep(const float* __restrict__ logits,
                       const float* __restrict__ W2,
                       unsigned char* __restrict__ ws)
{
  __shared__ float red[256];
  const int bid = blockIdx.x, tid = threadIdx.x;
  if (bid < 32) {
    int u    = (bid << 8) + tid;         // 0..8191 16B-units
    int col  = u & 127;                  // fastest -> coalesced W2 reads
    int rest = u >> 7;
    int k16l = rest & 15;
    int q    = rest >> 4;                // 0..3  (= c*2 + kh)
    int c    = q >> 1, kh = q & 1;
    int kbase = kh * 128 + k16l * 8;
    int j     = c * 128 + col;
    union { _Float16 h[8]; uint4 v; } pk;
    #pragma unroll
    for (int i = 0; i < 8; ++i)
      pk.h[i] = (_Float16)W2[(kbase + i) * 256 + j];
    unsigned off = (unsigned)q * 32768u + (unsigned)col * 256u
                 + (unsigned)((k16l ^ (col & 7)) << 4);
    *(uint4*)(ws + WS_W2IMG + off) = pk.v;
  } else if (bid == 32) {
    if (tid <= 32) {
      const double pi = 3.141592653589793238462643383279502884;
      float* steps = (float*)(ws + WS_STEPS);
      float* ccw   = (float*)(ws + WS_CCW);
      steps[tid] = (float)cos((double)tid * pi / 32.0);
      double acc = 0.0;
      for (int i = 0; i <= 32; i += 2) {           // odd i have Wv=0
        double wv = (i == 0) ? 1.0 : 2.0 / (1.0 - (double)(i * i));
        double L  = cos((double)(i * tid) * pi / 32.0);
        if (tid == 0)  L = 0.5;
        if (tid == 32) L *= 0.5;
        acc += L * wv;
      }
      ccw[tid] = (float)(acc * (1.0 / 16.0));      // * 2/nb
    }
  } else {
    // softmax for all 1024 rows in ONE block + min reduction
    float* x = (float*)(ws + WS_X);
    float lmin = 3.0e38f;
    #pragma unroll
    for (int k = 0; k < 4; ++k) {
      int r = k * 256 + tid;                       // 0..1023
      const float* row = logits + r * 10;
      float v[10]; float m = -3.0e38f;
      #pragma unroll
      for (int c = 0; c < 10; ++c) { v[c] = row[c]; m = fmaxf(m, v[c]); }
      float s = 0.f;
      #pragma unroll
      for (int c = 0; c < 10; ++c) s += __expf(v[c] - m);
      float lse = m + __logf(s);
      #pragma unroll
      for (int c = 0; c < 10; ++c) {
        float z = v[c] - lse;
        x[r * 10 + c] = z;
        lmin = fminf(lmin, z);
      }
    }
    red[tid] = lmin;
    __syncthreads();
    #pragma unroll
    for (int s = 128; s > 0; s >>= 1) {
      if (tid < s) red[tid] = fminf(red[tid], red[tid + s]);
      __syncthreads();
    }
    if (tid == 0) *(float*)(ws + WS_MINX) = red[0];
  }
}

// ---------------------------------------------------------------------------
// mlp: evaluate g on the GRID uniform t-grid over [min_x, 0].
// 96 rows/block, 4 waves (2 wm x 2 wn), A(h1) in registers, W2 quadrants
// double-buffered via global_load_lds. (round-4 k_main, t from grid index)
// ---------------------------------------------------------------------------
__global__ __launch_bounds__(256, 2) void k_mlp(
    const unsigned char* __restrict__ ws,
    const float* __restrict__ W1, const float* __restrict__ b1,
    const float* __restrict__ b2, const float* __restrict__ W3,
    const float* __restrict__ b3)
{
  __shared__ unsigned char smem[65536] __attribute__((aligned(16)));
  const int tid  = threadIdx.x;
  const int lane = tid & 63, wid = tid >> 6;
  const int wm = wid >> 1, wn = wid & 1;
  const int l15 = lane & 15, l4 = lane >> 4;

  const unsigned char* img = ws + WS_W2IMG;
  float* g_out = (float*)(const_cast<unsigned char*>(ws) + WS_G);
  const float minx   = *(const float*)(ws + WS_MINX);
  const float step_t = minx * (-1.0f / GM1);       // t_r = minx + r*step_t

  const int row_base = blockIdx.x * 96;

  // ---- issue stage(0) (quadrant 0 -> buf0), 8 x 1KB per wave ----
  #pragma unroll
  for (int i = 0; i < 8; ++i) {
    int off = wid * 1024 + i * 4096;
    gload_lds16(img + off + lane * 16, smem + off);
  }

  // ---- preload epilogue constants ----
  float b2r[2][4], w3r[2][4];
  #pragma unroll
  for (int c = 0; c < 2; ++c)
    #pragma unroll
    for (int bj = 0; bj < 4; ++bj) {
      int col = c * 128 + wn * 64 + bj * 16 + l15;
      b2r[c][bj] = b2[col];
      w3r[c][bj] = W3[col];
    }

  // ---- A fragments in registers: A[ai][ks], row=wm*48+ai*16+l15, k=ks*32+l4*8+j
  f16x8 A[3][8];
  {
    float t[3];
    #pragma unroll
    for (int ai = 0; ai < 3; ++ai) {
      int rg = row_base + wm * 48 + ai * 16 + l15;
      t[ai] = fmaf((float)rg, step_t, minx);
    }
    #pragma unroll
    for (int ks = 0; ks < 8; ++ks) {
      int k0 = ks * 32 + l4 * 8;
      float w1v[8], b1v[8];
      *(float4*)&w1v[0] = *(const float4*)(W1 + k0);
      *(float4*)&w1v[4] = *(const float4*)(W1 + k0 + 4);
      *(float4*)&b1v[0] = *(const float4*)(b1 + k0);
      *(float4*)&b1v[4] = *(const float4*)(b1 + k0 + 4);
      #pragma unroll
      for (int ai = 0; ai < 3; ++ai) {
        union { _Float16 h[8]; f16x8 v; } pk;
        #pragma unroll
        for (int j = 0; j < 8; ++j)
          pk.h[j] = (_Float16)elu1(fmaf(t[ai], w1v[j], b1v[j]));
        A[ai][ks] = pk.v;
      }
    }
  }
  __syncthreads();   // drains vmcnt(0): stage(0) landed for all waves

  float pacc[3][4];
  #pragma unroll
  for (int a = 0; a < 3; ++a)
    #pragma unroll
    for (int r = 0; r < 4; ++r) pacc[a][r] = 0.f;

  floatx4 acc[3][4];

  // ---- quadrant pipeline: q = c*2 + kh ----
  #pragma unroll
  for (int q = 0; q < 4; ++q) {
    const int buf = (q & 1) * 32768;
    if (q < 3) {                              // issue next stage -> buf^1
      const int nb = ((q + 1) & 1) * 32768;
      #pragma unroll
      for (int i = 0; i < 8; ++i) {
        int off = wid * 1024 + i * 4096;
        gload_lds16(img + (q + 1) * 32768 + off + lane * 16, smem + nb + off);
      }
    }
    if ((q & 1) == 0) {
      #pragma unroll
      for (int a = 0; a < 3; ++a)
        #pragma unroll
        for (int bj = 0; bj < 4; ++bj) acc[a][bj] = floatx4{0.f, 0.f, 0.f, 0.f};
    }
    const int kh = q & 1;
    #pragma unroll
    for (int kl = 0; kl < 4; ++kl) {
      const int ks = kh * 4 + kl;
      f16x8 bfr[4];
      #pragma unroll
      for (int bj = 0; bj < 4; ++bj) {
        int col  = wn * 64 + bj * 16 + l15;
        int unit = (kl * 4 + l4) ^ (col & 7);
        bfr[bj]  = *(const f16x8*)(smem + buf + col * 256 + (unit << 4));
      }
      #pragma unroll
      for (int ai = 0; ai < 3; ++ai)
        #pragma unroll
        for (int bj = 0; bj < 4; ++bj)
          acc[ai][bj] = __builtin_amdgcn_mfma_f32_16x16x32_f16(
              A[ai][ks], bfr[bj], acc[ai][bj], 0, 0, 0);
    }
    if (q & 1) {                              // epilogue for chunk c = q>>1
      const int c = q >> 1;
      #pragma unroll
      for (int bj = 0; bj < 4; ++bj) {
        float b2v = b2r[c][bj], w3v = w3r[c][bj];
        #pragma unroll
        for (int ai = 0; ai < 3; ++ai)
          #pragma unroll
          for (int rr = 0; rr < 4; ++rr)
            pacc[ai][rr] = fmaf(elu1(acc[ai][bj][rr] + b2v), w3v, pacc[ai][rr]);
      }
    }
    __syncthreads();
  }

  // ---- reduce: within-wave over 16 col-lanes, then across the wn pair ----
  float* part = (float*)smem;            // [wid][48], aliases buf0 (done)
  #pragma unroll
  for (int ai = 0; ai < 3; ++ai)
    #pragma unroll
    for (int rr = 0; rr < 4; ++rr) {
      float v = pacc[ai][rr];
      v += __shfl_xor(v, 1);
      v += __shfl_xor(v, 2);
      v += __shfl_xor(v, 4);
      v += __shfl_xor(v, 8);
      if (l15 == 0) part[wid * 48 + ai * 16 + l4 * 4 + rr] = v;
    }
  __syncthreads();
  if (tid < 96) {
    int wmr = tid / 48, r = tid - wmr * 48;
    float o = part[(wmr * 2) * 48 + r] + part[(wmr * 2 + 1) * 48 + r] + b3[0];
    g_out[row_base + wmr * 48 + r] = elu1(o) + 1.f;
  }
}

// ---------------------------------------------------------------------------
// interp: out[n] = (sum_s ccw[s] * lerp(g_grid, t_ns)) * x[n]*0.5 + offset
// g_grid (33KB) staged in LDS; t_ns = x[n]*(steps[s]+1)/2 on the uniform grid.
// ---------------------------------------------------------------------------
__global__ void k_interp(const unsigned char* __restrict__ ws,
                         const float* __restrict__ offset,
                         float* __restrict__ out)
{
  __shared__ float gs[GRID];
  __shared__ float st_l[33], cw_l[33];
  const int tid = threadIdx.x;
  const float* gg = (const float*)(ws + WS_G);
  for (int i = tid; i < GRID; i += 256) gs[i] = gg[i];
  if (tid < 33) {
    st_l[tid] = ((const float*)(ws + WS_STEPS))[tid];
    cw_l[tid] = ((const float*)(ws + WS_CCW))[tid];
  }
  __syncthreads();

  const int n = blockIdx.x * 256 + tid;          // 0..10239
  const float x    = ((const float*)(ws + WS_X))[n];
  const float minx = *(const float*)(ws + WS_MINX);
  const float xo   = x / minx;                   // in (0, 1]
  const float a    = xo * (0.5f * GM1);
  const float c0   = GM1 - a;
  float acc = 0.f;
  #pragma unroll 4
  for (int s = 0; s < 33; ++s) {
    float u = fmaf(-a, st_l[s], c0);             // grid coordinate of t_ns
    int i = (int)u;
    i = i > (GRID - 2) ? (GRID - 2) : i;
    i = i < 0 ? 0 : i;
    float f  = u - (float)i;
    float g0 = gs[i], g1 = gs[i + 1];
    acc = fmaf(cw_l[s], fmaf(f, g1 - g0, g0), acc);
  }
  out[n] = fmaf(acc, x * 0.5f, offset[0]);
}

extern "C" void kernel_launch(void* const* d_in, const int* in_sizes, int n_in,
                              void* d_out, int out_size, void* d_ws, size_t ws_size,
                              hipStream_t stream)
{
  const float* logits = (const float*)d_in[0];
  const float* W1     = (const float*)d_in[1];
  const float* b1     = (const float*)d_in[2];
  const float* W2     = (const float*)d_in[3];
  const float* b2     = (const float*)d_in[4];
  const float* W3     = (const float*)d_in[5];
  const float* b3     = (const float*)d_in[6];
  const float* offset = (const float*)d_in[7];
  unsigned char* ws   = (unsigned char*)d_ws;
  float* out          = (float*)d_out;

  k_prep<<<34, 256, 0, stream>>>(logits, W2, ws);
  k_mlp<<<NBLK_MLP, 256, 0, stream>>>(ws, W1, b1, b2, W3, b3);
  k_interp<<<40, 256, 0, stream>>>(ws, offset, out);
}